// Round 2
// baseline (418.343 us; speedup 1.0000x reference)
//
#include <hip/hip_runtime.h>

#define NB 32
#define H 384
#define W 640
#define NC 128
#define FH 96        // H/4
#define FWID 160     // W/4
#define BORDER 30
#define PTHRESH 0.015f
#define TOPK 2000
#define HW (H * W)   // 245760, multiple of 64

// r_shape may arrive as int32 (harness converts integers to int) or as raw
// int64. Under int64 little-endian layout, word [2b+1] is the high word of
// element b (384 or 640) and is therefore 0 -> unambiguous discriminator.
__device__ inline void load_rshape(const int* p32, int b, int* rs0, int* rs1) {
  const int a = p32[2 * b];
  const int c = p32[2 * b + 1];
  if (c == 0) {  // int64 storage
    const long long* p64 = (const long long*)p32;
    *rs0 = (int)p64[2 * b];
    *rs1 = (int)p64[2 * b + 1];
  } else {  // int32 storage
    *rs0 = a;
    *rs1 = c;
  }
}

// ---------------------------------------------------------------------------
// Kernel 1: one 64-lane wave per batch. Ordered stream-compaction of masked
// pixel linear indices (ascending), capped at TOPK, uniform early exit.
// No shared memory, no barriers: rank via ballot+popcount, running base is
// wave-uniform. Data slots [0,min(base,TOPK)) and sentinel slots
// [min(base,TOPK),TOPK) are disjoint -> exactly one writer per slot.
// stride lets the index land either densely in d_ws or overlaid at
// des[pk*NC] when ws is too small.
// ---------------------------------------------------------------------------
__global__ void compact_kernel(const float* __restrict__ prob,
                               const int* __restrict__ rsp,
                               int* __restrict__ out, int stride) {
  const int b = blockIdx.x;
  const int lane = threadIdx.x;  // blockDim.x == 64
  int rs0, rs1;
  load_rshape(rsp, b, &rs0, &rs1);
  const int ymax = rs0 - BORDER;
  const int xmax = rs1 - BORDER;
  const float* pb = prob + (size_t)b * HW;
  int* ob = out + (size_t)b * TOPK * stride;
  const unsigned long long ltmask = (1ull << lane) - 1ull;

  int base = 0;
  for (int i0 = 0; i0 < HW && base < TOPK; i0 += 64) {
    const int i = i0 + lane;  // always < HW (HW % 64 == 0)
    const int y = i / W;
    const int x = i - y * W;
    bool m = (y >= BORDER) && (y < ymax) && (x >= BORDER) && (x < xmax);
    if (m) m = pb[i] > PTHRESH;
    const unsigned long long mb = __ballot(m);
    const int pos = base + __popcll(mb & ltmask);
    if (m && pos < TOPK) ob[(size_t)pos * stride] = i;
    base += __popcll(mb);
  }
  const int filled = base < TOPK ? base : TOPK;
  for (int k = filled + lane; k < TOPK; k += 64)
    ob[(size_t)k * stride] = HW;  // sentinel
}

// ---------------------------------------------------------------------------
// Kernel 2: one 128-thread block per (b,k) point; thread = channel.
// All threads read the point index first, barrier, then write (required for
// the overlay path where the index lives inside the des slot being written).
// Bilinear fracs are exact multiples of 0.25 -> matches reference fp32 math.
// ---------------------------------------------------------------------------
__global__ void gather_kernel(const float* __restrict__ featmap,
                              const float* __restrict__ ratio,
                              const int* __restrict__ idx_base, int stride,
                              float* __restrict__ pts,
                              float* __restrict__ des) {
  const int pk = blockIdx.x;  // 0 .. NB*TOPK-1
  const int b = pk / TOPK;
  const int c = threadIdx.x;

  const int idx = idx_base[(size_t)pk * stride];
  __syncthreads();  // overlay safety: every lane reads before any lane writes

  const bool valid = (unsigned)idx < (unsigned)HW;
  const int ic = valid ? idx : 0;
  const int y = ic / W;
  const int x = ic - y * W;
  const int x0 = x >> 2;
  const int y0 = y >> 2;
  const float fx = (float)(x & 3) * 0.25f;
  const float fy = (float)(y & 3) * 0.25f;
  const float gx = 1.0f - fx, gy = 1.0f - fy;
  const float wa = gx * gy, wb = gx * fy, wc = fx * gy, wd = fx * fy;

  const float* fp = featmap + (((size_t)b * NC + c) * FH + y0) * FWID + x0;
  const float Ia = fp[0];
  const float Ic = fp[1];
  const float Ib = fp[FWID];
  const float Id = fp[FWID + 1];
  const float v = Ia * wa + Ib * wb + Ic * wc + Id * wd;
  des[(size_t)pk * NC + c] = valid ? v : 0.0f;

  if (c < 2) {
    const float p = (c == 0 ? (float)x : (float)y) / ratio[b];
    pts[pk * 2 + c] = valid ? p : 0.0f;
  }
}

extern "C" void kernel_launch(void* const* d_in, const int* in_sizes, int n_in,
                              void* d_out, int out_size, void* d_ws,
                              size_t ws_size, hipStream_t stream) {
  const float* prob = (const float*)d_in[0];     // (32,1,384,640) f32
  const float* featmap = (const float*)d_in[1];  // (32,128,96,160) f32
  const float* ratio = (const float*)d_in[2];    // (32,1) f32
  const int* r_shape = (const int*)d_in[3];      // (32,2) int (dtype sniffed)

  float* pts = (float*)d_out;                // (32,2000,2)
  float* des = pts + (size_t)NB * TOPK * 2;  // (32,2000,128)

  // Index scratch: prefer d_ws; if too small, overlay into des (stride NC).
  int* idx_base;
  int stride;
  if (ws_size >= (size_t)NB * TOPK * sizeof(int)) {
    idx_base = (int*)d_ws;
    stride = 1;
  } else {
    idx_base = (int*)des;
    stride = NC;
  }

  compact_kernel<<<NB, 64, 0, stream>>>(prob, r_shape, idx_base, stride);
  gather_kernel<<<NB * TOPK, 128, 0, stream>>>(featmap, ratio, idx_base,
                                               stride, pts, des);
}

// Round 3
// 370.219 us; speedup vs baseline: 1.1300x; 1.1300x over previous
//
#include <hip/hip_runtime.h>

#define NB 32
#define H 384
#define W 640
#define NC 128
#define FH 96        // H/4
#define FWID 160     // W/4
#define BORDER 30
#define PTHRESH 0.015f
#define TOPK 2000
#define HW (H * W)   // 245760
#define NWAVE 4      // waves per compact block (256 threads)
#define NXIT 10      // 640 / 64 ballot iterations per row

// r_shape may arrive as int32 (harness-converted) or raw int64. Under int64
// little-endian layout, word [2b+1] is the high word of element b (384/640)
// and is therefore 0 -> unambiguous discriminator.
__device__ inline void load_rshape(const int* p32, int b, int* rs0, int* rs1) {
  const int a = p32[2 * b];
  const int c = p32[2 * b + 1];
  if (c == 0) {  // int64 storage
    const long long* p64 = (const long long*)p32;
    *rs0 = (int)p64[2 * b];
    *rs1 = (int)p64[2 * b + 1];
  } else {  // int32 storage
    *rs0 = a;
    *rs1 = c;
  }
}

// ---------------------------------------------------------------------------
// Kernel 1: per-batch ordered compaction, parallel chunked row-scan.
// 256 threads = 4 waves per batch. Each chunk: wave w scans row row0+w with
// 10 independent (pipelined) loads, keeping ballot masks in registers;
// LDS-exchange the 4 row counts; prefix; write phase replays stored ballots.
// Uniform early exit once cumulative count >= TOPK. Rows 0..BORDER-1 and
// ymax.. are never touched.
// ---------------------------------------------------------------------------
__global__ __launch_bounds__(256) void compact_kernel(
    const float* __restrict__ prob, const int* __restrict__ rsp,
    int* __restrict__ out, int stride) {
  const int b = blockIdx.x;
  const int tid = threadIdx.x;
  const int lane = tid & 63;
  const int wv = tid >> 6;  // 0..3
  int rs0, rs1;
  load_rshape(rsp, b, &rs0, &rs1);
  const int ymax = rs0 - BORDER;  // valid rows: [BORDER, ymax)
  const int xmax = rs1 - BORDER;  // valid cols: [BORDER, xmax)
  const float* pb = prob + (size_t)b * HW;
  int* ob = out + (size_t)b * TOPK * stride;
  const unsigned long long ltmask = (1ull << lane) - 1ull;

  __shared__ int s_cnt[NWAVE];

  int chunk_base = 0;
  for (int row0 = BORDER; row0 < ymax && chunk_base < TOPK; row0 += NWAVE) {
    const int r = row0 + wv;
    unsigned long long mbs[NXIT];
    int cnt = 0;
    if (r < ymax) {
      const float* rowp = pb + r * W;
#pragma unroll
      for (int t = 0; t < NXIT; ++t) {
        const int x = t * 64 + lane;
        const bool m = (x >= BORDER) && (x < xmax) && (rowp[x] > PTHRESH);
        mbs[t] = __ballot(m);
        cnt += __popcll(mbs[t]);
      }
    } else {
#pragma unroll
      for (int t = 0; t < NXIT; ++t) mbs[t] = 0;
    }
    if (lane == 0) s_cnt[wv] = cnt;
    __syncthreads();
    int row_start = chunk_base;
    int total = 0;
#pragma unroll
    for (int j = 0; j < NWAVE; ++j) {
      const int cj = s_cnt[j];
      if (j < wv) row_start += cj;
      total += cj;
    }
    if (cnt > 0 && row_start < TOPK) {
      int rank = row_start;
      const int ibase = r * W;
#pragma unroll
      for (int t = 0; t < NXIT; ++t) {
        const unsigned long long mb = mbs[t];
        const bool m = (mb >> lane) & 1ull;
        const int pos = rank + __popcll(mb & ltmask);
        if (m && pos < TOPK) ob[(size_t)pos * stride] = ibase + t * 64 + lane;
        rank += __popcll(mb);
      }
    }
    chunk_base += total;
    __syncthreads();  // protect s_cnt before next chunk overwrites it
  }
  // sentinel-fill any unfilled tail slots
  const int filled = chunk_base < TOPK ? chunk_base : TOPK;
  for (int k = filled + tid; k < TOPK; k += 256)
    ob[(size_t)k * stride] = HW;
}

// ---------------------------------------------------------------------------
// Kernel 2: one 128-thread block per (b,k) point; thread = channel.
// des writes coalesced (512B/block). Bilinear fracs are exact multiples of
// 0.25 -> bit-matches reference fp32 arithmetic (absmax 0.0 in r2).
// ---------------------------------------------------------------------------
__global__ __launch_bounds__(128) void gather_kernel(
    const float* __restrict__ featmap, const float* __restrict__ ratio,
    const int* __restrict__ idx_base, int stride, float* __restrict__ pts,
    float* __restrict__ des) {
  const int k = blockIdx.x;   // 0..TOPK-1
  const int b = blockIdx.y;   // 0..NB-1
  const int pk = b * TOPK + k;
  const int c = threadIdx.x;

  const int idx = idx_base[(size_t)pk * stride];
  __syncthreads();  // overlay safety: all lanes read before any lane writes

  const bool valid = (unsigned)idx < (unsigned)HW;
  const int ic = valid ? idx : 0;
  const int y = ic / W;
  const int x = ic - y * W;
  const int x0 = x >> 2;
  const int y0 = y >> 2;
  const float fx = (float)(x & 3) * 0.25f;
  const float fy = (float)(y & 3) * 0.25f;
  const float gx = 1.0f - fx, gy = 1.0f - fy;
  const float wa = gx * gy, wb = gx * fy, wc = fx * gy, wd = fx * fy;

  const float* fp = featmap + (((size_t)b * NC + c) * FH + y0) * FWID + x0;
  const float Ia = fp[0];
  const float Ic = fp[1];
  const float Ib = fp[FWID];
  const float Id = fp[FWID + 1];
  const float v = Ia * wa + Ib * wb + Ic * wc + Id * wd;
  des[(size_t)pk * NC + c] = valid ? v : 0.0f;

  if (c < 2) {
    const float p = (c == 0 ? (float)x : (float)y) / ratio[b];
    pts[pk * 2 + c] = valid ? p : 0.0f;
  }
}

extern "C" void kernel_launch(void* const* d_in, const int* in_sizes, int n_in,
                              void* d_out, int out_size, void* d_ws,
                              size_t ws_size, hipStream_t stream) {
  const float* prob = (const float*)d_in[0];     // (32,1,384,640) f32
  const float* featmap = (const float*)d_in[1];  // (32,128,96,160) f32
  const float* ratio = (const float*)d_in[2];    // (32,1) f32
  const int* r_shape = (const int*)d_in[3];      // (32,2) int (dtype sniffed)

  float* pts = (float*)d_out;                // (32,2000,2)
  float* des = pts + (size_t)NB * TOPK * 2;  // (32,2000,128)

  // Index scratch: prefer d_ws; if too small, overlay into des (stride NC).
  int* idx_base;
  int stride;
  if (ws_size >= (size_t)NB * TOPK * sizeof(int)) {
    idx_base = (int*)d_ws;
    stride = 1;
  } else {
    idx_base = (int*)des;
    stride = NC;
  }

  compact_kernel<<<NB, 256, 0, stream>>>(prob, r_shape, idx_base, stride);
  dim3 ggrid(TOPK, NB);
  gather_kernel<<<ggrid, 128, 0, stream>>>(featmap, ratio, idx_base, stride,
                                           pts, des);
}

// Round 4
// 325.983 us; speedup vs baseline: 1.2833x; 1.1357x over previous
//
#include <hip/hip_runtime.h>

#define NB 32
#define H 384
#define W 640
#define NC 128
#define FH 96        // H/4
#define FWID 160     // W/4
#define BORDER 30
#define PTHRESH 0.015f
#define TOPK 2000
#define HW (H * W)   // 245760
#define NWAVE 4      // waves per compact block (256 threads)
#define NXIT 10      // 640 / 64 ballot iterations per row
#define PTILE 64     // points per gather block
#define NTILE ((TOPK + PTILE - 1) / PTILE)  // 32 (tile 31 has 16 pts)

// r_shape may arrive as int32 (harness-converted) or raw int64. Under int64
// little-endian layout, word [2b+1] is the high word of element b (384/640)
// and is therefore 0 -> unambiguous discriminator.
__device__ inline void load_rshape(const int* p32, int b, int* rs0, int* rs1) {
  const int a = p32[2 * b];
  const int c = p32[2 * b + 1];
  if (c == 0) {  // int64 storage
    const long long* p64 = (const long long*)p32;
    *rs0 = (int)p64[2 * b];
    *rs1 = (int)p64[2 * b + 1];
  } else {  // int32 storage
    *rs0 = a;
    *rs1 = c;
  }
}

// ---------------------------------------------------------------------------
// Kernel 1: per-batch ordered compaction, parallel chunked row-scan.
// 256 threads = 4 waves per batch; wave w scans row row0+w (10 pipelined
// loads, ballots kept in registers); LDS-exchange row counts; prefix; replay
// stored ballots to write. Uniform early exit once >= TOPK found. At ~571
// hits/row this exits after one chunk (rows 30-33).
// ---------------------------------------------------------------------------
__global__ __launch_bounds__(256) void compact_kernel(
    const float* __restrict__ prob, const int* __restrict__ rsp,
    int* __restrict__ out, int stride) {
  const int b = blockIdx.x;
  const int tid = threadIdx.x;
  const int lane = tid & 63;
  const int wv = tid >> 6;  // 0..3
  int rs0, rs1;
  load_rshape(rsp, b, &rs0, &rs1);
  const int ymax = rs0 - BORDER;  // valid rows: [BORDER, ymax)
  const int xmax = rs1 - BORDER;  // valid cols: [BORDER, xmax)
  const float* pb = prob + (size_t)b * HW;
  int* ob = out + (size_t)b * TOPK * stride;
  const unsigned long long ltmask = (1ull << lane) - 1ull;

  __shared__ int s_cnt[NWAVE];

  int chunk_base = 0;
  for (int row0 = BORDER; row0 < ymax && chunk_base < TOPK; row0 += NWAVE) {
    const int r = row0 + wv;
    unsigned long long mbs[NXIT];
    int cnt = 0;
    if (r < ymax) {
      const float* rowp = pb + r * W;
#pragma unroll
      for (int t = 0; t < NXIT; ++t) {
        const int x = t * 64 + lane;
        const bool m = (x >= BORDER) && (x < xmax) && (rowp[x] > PTHRESH);
        mbs[t] = __ballot(m);
        cnt += __popcll(mbs[t]);
      }
    } else {
#pragma unroll
      for (int t = 0; t < NXIT; ++t) mbs[t] = 0;
    }
    if (lane == 0) s_cnt[wv] = cnt;
    __syncthreads();
    int row_start = chunk_base;
    int total = 0;
#pragma unroll
    for (int j = 0; j < NWAVE; ++j) {
      const int cj = s_cnt[j];
      if (j < wv) row_start += cj;
      total += cj;
    }
    if (cnt > 0 && row_start < TOPK) {
      int rank = row_start;
      const int ibase = r * W;
#pragma unroll
      for (int t = 0; t < NXIT; ++t) {
        const unsigned long long mb = mbs[t];
        const bool m = (mb >> lane) & 1ull;
        const int pos = rank + __popcll(mb & ltmask);
        if (m && pos < TOPK) ob[(size_t)pos * stride] = ibase + t * 64 + lane;
        rank += __popcll(mb);
      }
    }
    chunk_base += total;
    __syncthreads();  // protect s_cnt before next chunk overwrites it
  }
  const int filled = chunk_base < TOPK ? chunk_base : TOPK;
  for (int k = filled + tid; k < TOPK; k += 256)
    ob[(size_t)k * stride] = HW;  // sentinel
}

// ---------------------------------------------------------------------------
// Kernel 2: tiled gather. One 256-thread block per 64-point tile.
// Lane = point, loop over channels: consecutive accepted points are nearly
// consecutive in x, so each 64-lane tap load hits ~2 cache lines (vs 64 with
// lane=channel). Results staged in LDS [NC][PTILE+1] (conflict-free writes
// along points, conflict-free reads along channels), then written out fully
// coalesced (contiguous 32 KB per full tile).
// ---------------------------------------------------------------------------
__global__ __launch_bounds__(256) void gather_kernel(
    const float* __restrict__ featmap, const float* __restrict__ ratio,
    const int* __restrict__ idx_base, int stride, float* __restrict__ pts,
    float* __restrict__ des) {
  const int tile = blockIdx.x;  // 0..NTILE-1
  const int b = blockIdx.y;     // 0..NB-1
  const int k0 = tile * PTILE;
  const int npts = (TOPK - k0) < PTILE ? (TOPK - k0) : PTILE;
  const int pk0 = b * TOPK + k0;
  const int tid = threadIdx.x;
  const int lane = tid & 63;
  const int wv = tid >> 6;  // 0..3

  __shared__ int s_idx[PTILE];
  __shared__ float s_tile[NC][PTILE + 1];

  if (tid < PTILE)
    s_idx[tid] = (tid < npts) ? idx_base[(size_t)(pk0 + tid) * stride] : HW;
  __syncthreads();

  // per-lane point parameters (lane = point within tile)
  const int idx = s_idx[lane];
  const bool valid = (unsigned)idx < (unsigned)HW;
  const int ic = valid ? idx : 0;
  const int y = ic / W;
  const int x = ic - y * W;
  const int x0 = x >> 2;
  const int y0 = y >> 2;
  const float fx = (float)(x & 3) * 0.25f;
  const float fy = (float)(y & 3) * 0.25f;
  const float gx = 1.0f - fx, gy = 1.0f - fy;
  float wa = gx * gy, wb = gx * fy, wc = fx * gy, wd = fx * fy;
  if (!valid) wa = wb = wc = wd = 0.0f;  // -> v = 0 exactly

  const float* fp0 = featmap + (((size_t)b * NC) * FH + y0) * FWID + x0;
#pragma unroll 4
  for (int j = 0; j < NC / 4; ++j) {
    const int c = wv * (NC / 4) + j;
    const float* fp = fp0 + (size_t)c * (FH * FWID);
    const float Ia = fp[0];
    const float Ic = fp[1];
    const float Ib = fp[FWID];
    const float Id = fp[FWID + 1];
    s_tile[c][lane] = Ia * wa + Ib * wb + Ic * wc + Id * wd;
  }

  if (wv == 0 && lane < npts) {
    const float r = ratio[b];
    pts[(size_t)(pk0 + lane) * 2 + 0] = valid ? (float)x / r : 0.0f;
    pts[(size_t)(pk0 + lane) * 2 + 1] = valid ? (float)y / r : 0.0f;
  }

  __syncthreads();

  // coalesced write-out: thread t -> channel (t&127), points step 2
  float* db = des + (size_t)pk0 * NC;
  const int c = tid & 127;
  for (int k = tid >> 7; k < npts; k += 2)
    db[(size_t)k * NC + c] = s_tile[c][k];
}

extern "C" void kernel_launch(void* const* d_in, const int* in_sizes, int n_in,
                              void* d_out, int out_size, void* d_ws,
                              size_t ws_size, hipStream_t stream) {
  const float* prob = (const float*)d_in[0];     // (32,1,384,640) f32
  const float* featmap = (const float*)d_in[1];  // (32,128,96,160) f32
  const float* ratio = (const float*)d_in[2];    // (32,1) f32
  const int* r_shape = (const int*)d_in[3];      // (32,2) int (dtype sniffed)

  float* pts = (float*)d_out;                // (32,2000,2)
  float* des = pts + (size_t)NB * TOPK * 2;  // (32,2000,128)

  // Index scratch: prefer d_ws; if too small, overlay into des (stride NC).
  int* idx_base;
  int stride;
  if (ws_size >= (size_t)NB * TOPK * sizeof(int)) {
    idx_base = (int*)d_ws;
    stride = 1;
  } else {
    idx_base = (int*)des;
    stride = NC;
  }

  compact_kernel<<<NB, 256, 0, stream>>>(prob, r_shape, idx_base, stride);
  dim3 ggrid(NTILE, NB);
  gather_kernel<<<ggrid, 256, 0, stream>>>(featmap, ratio, idx_base, stride,
                                           pts, des);
}